// Round 3
// baseline (1079.880 us; speedup 1.0000x reference)
//
#include <hip/hip_runtime.h>
#include <math.h>

#define DIM_  768
#define INT_  512
#define NE    8
#define MROWS 48                 // tokens per tile
#define PERMAT 393216            // u32s per (expert,matrix): 768 frags * 64 lanes * 8

typedef unsigned int u32;
typedef unsigned short u16;
typedef __attribute__((ext_vector_type(4))) u32   u32x4;
typedef __attribute__((ext_vector_type(8))) short bf16x8;
typedef __attribute__((ext_vector_type(4))) float f32x4;

#define MFMA(acc, a, b) acc = __builtin_amdgcn_mfma_f32_16x16x32_bf16(a, b, acc, 0, 0, 0)

static __device__ __forceinline__ u16 f2bf(float f) {      // RNE float->bf16
  u32 u = __builtin_bit_cast(u32, f);
  return (u16)((u + 0x7fffu + ((u >> 16) & 1u)) >> 16);
}
static __device__ __forceinline__ float bf2f(u16 s) {
  u32 u = ((u32)s) << 16; return __builtin_bit_cast(float, u);
}
// swizzled word offset in a [rows][L u32] LDS plane; XOR on 16B granules,
// bijective within each row, identical at write & read -> correctness-neutral
template<int L>
static __device__ __forceinline__ int swoff(int row, int wi) {
  int g = (wi >> 2) ^ ((row & 7) << 1);
  return row * L + ((g & (L / 4 - 1)) << 2) + (wi & 3);
}

// ---------------------------------------------------------------------------
// routing (unchanged logic from fp32 rounds)
// ---------------------------------------------------------------------------
__global__ void init_kernel(int* cnt, int* cur) {
  int t = threadIdx.x;
  if (t < 16) { cnt[t] = 0; cur[t] = 0; }
}

__global__ void gate_kernel(const float* __restrict__ x,
                            const float* __restrict__ gw,
                            const float* __restrict__ gb,
                            int* __restrict__ idx, float* __restrict__ wgt,
                            int* __restrict__ cnt, int T) {
  __shared__ float gws[NE * DIM_];
  __shared__ float gbs[NE];
  const int tid = threadIdx.x;
#pragma unroll
  for (int u = 0; u < 6; ++u) {
    int f = u * 256 + tid;
    ((float4*)gws)[f] = ((const float4*)gw)[f];
  }
  if (tid < NE) gbs[tid] = gb[tid];
  __syncthreads();

  const int lane = tid & 63;
  const int t = blockIdx.x * 4 + (tid >> 6);
  if (t >= T) return;

  float acc[NE] = {};
  const float* xr = x + (size_t)t * DIM_;
  for (int j = lane; j < DIM_; j += 64) {
    float xv = xr[j];
#pragma unroll
    for (int e = 0; e < NE; ++e) acc[e] = fmaf(xv, gws[e * DIM_ + j], acc[e]);
  }
#pragma unroll
  for (int e = 0; e < NE; ++e) {
#pragma unroll
    for (int off = 32; off > 0; off >>= 1) acc[e] += __shfl_xor(acc[e], off);
  }
  if (lane == 0) {
    float sc[NE], s[NE];
#pragma unroll
    for (int e = 0; e < NE; ++e) {
      sc[e] = 1.0f / (1.0f + expf(-acc[e]));
      s[e]  = sc[e] + gbs[e];
    }
    float gsc[4];
#pragma unroll
    for (int g = 0; g < 4; ++g) gsc[g] = s[2*g] + s[2*g+1];
    int g1 = 0;
    for (int g = 1; g < 4; ++g) if (gsc[g] > gsc[g1]) g1 = g;
    int g2 = (g1 == 0) ? 1 : 0;
    for (int g = 0; g < 4; ++g) if (g != g1 && gsc[g] > gsc[g2]) g2 = g;
    unsigned mask = (3u << (2*g1)) | (3u << (2*g2));
    int e1 = -1, e2 = -1;
    for (int e = 0; e < NE; ++e) if (mask & (1u<<e)) { if (e1 < 0 || s[e] > s[e1]) e1 = e; }
    for (int e = 0; e < NE; ++e) if ((mask & (1u<<e)) && e != e1) { if (e2 < 0 || s[e] > s[e2]) e2 = e; }
    float wa = sc[e1], wb = sc[e2];
    float inv = 1.0f / (wa + wb + 1e-6f);
    wa *= inv; wb *= inv;
    idx[2*t] = e1; idx[2*t+1] = e2;
    wgt[2*t] = wa; wgt[2*t+1] = wb;
    atomicAdd(&cnt[e1], 1);
    atomicAdd(&cnt[8 + e2], 1);
  }
}

__global__ void scan_kernel(const int* __restrict__ cnt, int* __restrict__ offs) {
  if (threadIdx.x == 0) {
    int a = 0;
    for (int L = 0; L < 16; ++L) { offs[L] = a; a += cnt[L]; }
  }
}

__global__ void scatter_kernel(const int* __restrict__ idx, const float* __restrict__ wgt,
                               const int* __restrict__ offs, int* __restrict__ cur,
                               int* __restrict__ tok, float* __restrict__ wof, int T) {
  int t = blockIdx.x * blockDim.x + threadIdx.x;
  if (t >= T) return;
#pragma unroll
  for (int s2 = 0; s2 < 2; ++s2) {
    int e = idx[2*t + s2];
    int L = s2 * 8 + e;
    int p = atomicAdd(&cur[L], 1);
    tok[offs[L] + p] = t;
    wof[offs[L] + p] = wgt[2*t + s2];
  }
}

// ---------------------------------------------------------------------------
// prep: split fp32 weights into hi/lo bf16 and pack fragment-major.
// Fragment (lane l): col = nb*16 + (l&15), k = ks*32 + (l>>4)*8 + j (j=0..7).
// Per lane: 4 u32 hi then 4 u32 lo (u32_i = bf16(k+2i) | bf16(k+2i+1)<<16).
// Experts 0..7 = routed, expert 8 = shared MLP.
// ---------------------------------------------------------------------------
__global__ __launch_bounds__(256)
void prep_kernel(const float* __restrict__ w1, const float* __restrict__ w3,
                 const float* __restrict__ w2, const float* __restrict__ sw1,
                 const float* __restrict__ sw3, const float* __restrict__ sw2,
                 u32* __restrict__ P1, u32* __restrict__ P3, u32* __restrict__ P2) {
  const int PER = 9 * 768 * 64;                 // 442368 lane-slots per matrix set
  int gid = blockIdx.x * 256 + threadIdx.x;
  int which = gid / PER;
  int r = gid % PER;
  int lane = r & 63;
  int fe = r >> 6;
  int fs = fe % 768;                            // frag-slot within expert
  int e  = fe / 768;                            // 0..8
  int c16 = lane & 15, q = lane >> 4;

  const float* src; u32* dst;
  if (which < 2) {                              // w1 / w3: [512 cols][768 k]
    int nb = fs / 24, ks = fs % 24;
    int col = nb * 16 + c16, k0 = ks * 32 + q * 8;
    const float* wm = (which == 0) ? w1 : w3;
    const float* sm = (which == 0) ? sw1 : sw3;
    src = (e < 8) ? wm + ((size_t)e * INT_ + col) * DIM_ + k0
                  : sm + (size_t)col * DIM_ + k0;
    dst = ((which == 0) ? P1 : P3) + ((size_t)(e * 768 + fs) * 64 + lane) * 8;
  } else {                                      // w2: [768 cols][512 k]
    int nb = fs / 16, ks = fs % 16;
    int col = nb * 16 + c16, k0 = ks * 32 + q * 8;
    src = (e < 8) ? w2 + ((size_t)e * DIM_ + col) * INT_ + k0
                  : sw2 + (size_t)col * INT_ + k0;
    dst = P2 + ((size_t)(e * 768 + fs) * 64 + lane) * 8;
  }
  float4 a = *(const float4*)src;
  float4 b = *(const float4*)(src + 4);
  u16 h0=f2bf(a.x), h1=f2bf(a.y), h2=f2bf(a.z), h3=f2bf(a.w);
  u16 h4=f2bf(b.x), h5=f2bf(b.y), h6=f2bf(b.z), h7=f2bf(b.w);
  u32x4 H = { (u32)h0|((u32)h1<<16), (u32)h2|((u32)h3<<16),
              (u32)h4|((u32)h5<<16), (u32)h6|((u32)h7<<16) };
  u32x4 Lv = { (u32)f2bf(a.x-bf2f(h0)) | ((u32)f2bf(a.y-bf2f(h1))<<16),
               (u32)f2bf(a.z-bf2f(h2)) | ((u32)f2bf(a.w-bf2f(h3))<<16),
               (u32)f2bf(b.x-bf2f(h4)) | ((u32)f2bf(b.y-bf2f(h5))<<16),
               (u32)f2bf(b.z-bf2f(h6)) | ((u32)f2bf(b.w-bf2f(h7))<<16) };
  *(u32x4*)dst = H;
  *(u32x4*)(dst + 4) = Lv;
}

// ---------------------------------------------------------------------------
// Fused SwiGLU expert, split-bf16 MFMA (D = Ah·Bh + Al·Bh + Ah·Bl, fp32 acc).
// 48-token tile, 8 waves. Phase 1: each wave owns 64 INTER cols of BOTH w1,w3
// (4 n-frags), K=768 in 3 LDS chunks of 256. Phase 2: each wave owns 96 DIM
// cols (6 n-frags), K=512 from Hs planes.
// LDS: Xh/Xl[48][128 u32] + Hh/Hl[48][256 u32] + rts/wrs = 147,840 B.
// ---------------------------------------------------------------------------
template<bool SHARED>
__global__ __launch_bounds__(512, 2)
void expert_mfma(const float* __restrict__ x,
                 const u32* __restrict__ P1, const u32* __restrict__ P3,
                 const u32* __restrict__ P2,
                 const int* __restrict__ cnt, const int* __restrict__ offs,
                 const int* __restrict__ tok, const float* __restrict__ wof,
                 float* __restrict__ out, int T, int slot, int tpe, int nwg) {
  extern __shared__ u32 sm[];
  u32* Xh = sm;                    // 48*128
  u32* Xl = Xh + 6144;
  u32* Hh = Xl + 6144;             // 48*256
  u32* Hl = Hh + 12288;
  int*   rts_s = (int*)(Hl + 12288);
  float* wrs_s = (float*)(rts_s + MROWS);

  // bijective XCD-chunked remap (m204)
  int orig = blockIdx.x;
  int q8 = nwg >> 3, rr = nwg & 7, xcd = orig & 7, pos = orig >> 3;
  int wgid = (xcd < rr ? xcd * (q8 + 1) : rr * (q8 + 1) + (xcd - rr) * q8) + pos;

  int e, n, off0, tile;
  if (SHARED) { e = 8; tile = wgid; n = T; off0 = 0; }
  else {
    e = wgid / tpe; tile = wgid % tpe;
    int L = slot * 8 + e;
    n = cnt[L]; off0 = offs[L];
  }
  const int r0 = tile * MROWS;
  if (r0 >= n) return;
  const int nr = min(MROWS, n - r0);
  const int tid = threadIdx.x;

  if (tid < MROWS) {
    int r = r0 + tid;
    if (SHARED) { rts_s[tid] = min(r, T - 1); wrs_s[tid] = 1.0f; }
    else {
      int rc = min(r, n - 1);
      rts_s[tid] = tok[off0 + rc];
      wrs_s[tid] = (r < n) ? wof[off0 + r] : 0.0f;
    }
  }
  __syncthreads();

  const int lane = tid & 63, wid = tid >> 6;
  const int c16 = lane & 15, q = lane >> 4;
  const u32* P1e = P1 + (size_t)e * PERMAT;
  const u32* P3e = P3 + (size_t)e * PERMAT;
  const u32* P2e = P2 + (size_t)e * PERMAT;

  // ---------------- phase 1 ----------------
  f32x4 acc1[3][4] = {};
  f32x4 acc3[3][4] = {};
  for (int ch = 0; ch < 3; ++ch) {
    __syncthreads();
    {
      const int cb = ch * 256;
#pragma unroll
      for (int u = 0; u < 6; ++u) {             // 3072 float4: 48 rows x 64
        int f = u * 512 + tid;
        int row = f >> 6, kq = f & 63;
        float4 v = *(const float4*)&x[(size_t)rts_s[row] * DIM_ + cb + kq * 4];
        u16 a0 = f2bf(v.x), a1 = f2bf(v.y), a2 = f2bf(v.z), a3 = f2bf(v.w);
        int base = swoff<128>(row, kq * 2);
        Xh[base]     = (u32)a0 | ((u32)a1 << 16);
        Xh[base + 1] = (u32)a2 | ((u32)a3 << 16);
        Xl[base]     = (u32)f2bf(v.x - bf2f(a0)) | ((u32)f2bf(v.y - bf2f(a1)) << 16);
        Xl[base + 1] = (u32)f2bf(v.z - bf2f(a2)) | ((u32)f2bf(v.w - bf2f(a3)) << 16);
      }
    }
    __syncthreads();
    for (int ks = 0; ks < 8; ++ks) {
      bf16x8 Ah[3], Al[3];
#pragma unroll
      for (int m = 0; m < 3; ++m) {
        int row = 16 * m + c16;
        int wi = ks * 16 + q * 4;
        Ah[m] = __builtin_bit_cast(bf16x8, *(const u32x4*)&Xh[swoff<128>(row, wi)]);
        Al[m] = __builtin_bit_cast(bf16x8, *(const u32x4*)&Xl[swoff<128>(row, wi)]);
      }
      const int gks = ch * 8 + ks;
#pragma unroll
      for (int nf = 0; nf < 4; ++nf) {
        int nb = wid * 4 + nf;
        const u32* p1 = P1e + ((size_t)(nb * 24 + gks) * 64 + lane) * 8;
        const u32* p3 = P3e + ((size_t)(nb * 24 + gks) * 64 + lane) * 8;
        bf16x8 B1h = __builtin_bit_cast(bf16x8, *(const u32x4*)p1);
        bf16x8 B1l = __builtin_bit_cast(bf16x8, *(const u32x4*)(p1 + 4));
        bf16x8 B3h = __builtin_bit_cast(bf16x8, *(const u32x4*)p3);
        bf16x8 B3l = __builtin_bit_cast(bf16x8, *(const u32x4*)(p3 + 4));
#pragma unroll
        for (int m = 0; m < 3; ++m) {
          MFMA(acc1[m][nf], Ah[m], B1h);
          MFMA(acc1[m][nf], Al[m], B1h);
          MFMA(acc1[m][nf], Ah[m], B1l);
          MFMA(acc3[m][nf], Ah[m], B3h);
          MFMA(acc3[m][nf], Al[m], B3h);
          MFMA(acc3[m][nf], Ah[m], B3l);
        }
      }
    }
  }
  // phase-1 epilogue: h = silu(a1)*a3, split hi/lo into Hs planes
  {
    u16* Hh16 = (u16*)Hh;
    u16* Hl16 = (u16*)Hl;
#pragma unroll
    for (int m = 0; m < 3; ++m)
#pragma unroll
      for (int nf = 0; nf < 4; ++nf)
#pragma unroll
        for (int reg = 0; reg < 4; ++reg) {
          int tokr = 16 * m + 4 * q + reg;            // C/D: row=(l>>4)*4+reg
          int col  = (wid * 4 + nf) * 16 + c16;       //       col=l&15
          float v1 = acc1[m][nf][reg], v3 = acc3[m][nf][reg];
          float h = v1 / (1.0f + expf(-v1)) * v3;
          u16 hh = f2bf(h);
          u16 hl = f2bf(h - bf2f(hh));
          int wo = swoff<256>(tokr, col >> 1);
          Hh16[wo * 2 + (col & 1)] = hh;
          Hl16[wo * 2 + (col & 1)] = hl;
        }
  }
  __syncthreads();

  // ---------------- phase 2 ----------------
  f32x4 acc2[3][6] = {};
  for (int ks = 0; ks < 16; ++ks) {
    bf16x8 Ah[3], Al[3];
#pragma unroll
    for (int m = 0; m < 3; ++m) {
      int row = 16 * m + c16;
      int wi = ks * 16 + q * 4;
      Ah[m] = __builtin_bit_cast(bf16x8, *(const u32x4*)&Hh[swoff<256>(row, wi)]);
      Al[m] = __builtin_bit_cast(bf16x8, *(const u32x4*)&Hl[swoff<256>(row, wi)]);
    }
#pragma unroll
    for (int nf = 0; nf < 6; ++nf) {
      int nb = wid * 6 + nf;
      const u32* p2 = P2e + ((size_t)(nb * 16 + ks) * 64 + lane) * 8;
      bf16x8 Bh = __builtin_bit_cast(bf16x8, *(const u32x4*)p2);
      bf16x8 Bl = __builtin_bit_cast(bf16x8, *(const u32x4*)(p2 + 4));
#pragma unroll
      for (int m = 0; m < 3; ++m) {
        MFMA(acc2[m][nf], Ah[m], Bh);
        MFMA(acc2[m][nf], Al[m], Bh);
        MFMA(acc2[m][nf], Ah[m], Bl);
      }
    }
  }
  // epilogue: scale by combine weight; SHARED plain-stores (init), routed RMW
#pragma unroll
  for (int m = 0; m < 3; ++m)
#pragma unroll
    for (int reg = 0; reg < 4; ++reg) {
      int tr = 16 * m + 4 * q + reg;
      if (tr < nr) {
        int gt = rts_s[tr];
        float wv = wrs_s[tr];
        float* po = out + (size_t)gt * DIM_ + c16;
#pragma unroll
        for (int nf = 0; nf < 6; ++nf) {
          int col = (wid * 6 + nf) * 16;
          float val = acc2[m][nf][reg] * wv;
          if (SHARED) po[col] = val;
          else        po[col] += val;           // race-free: slot launches serialized
        }
      }
    }
}

// ---------------------------------------------------------------------------
extern "C" void kernel_launch(void* const* d_in, const int* in_sizes, int n_in,
                              void* d_out, int out_size, void* d_ws, size_t ws_size,
                              hipStream_t stream) {
  const float* x   = (const float*)d_in[0];
  const float* gw  = (const float*)d_in[1];
  const float* gb  = (const float*)d_in[2];
  const float* w1  = (const float*)d_in[3];
  const float* w2  = (const float*)d_in[4];
  const float* w3  = (const float*)d_in[5];
  const float* sw1 = (const float*)d_in[6];
  const float* sw2 = (const float*)d_in[7];
  const float* sw3 = (const float*)d_in[8];
  float* out = (float*)d_out;
  const int T = in_sizes[0] / DIM_;            // 16384

  // ws: P1|P3|P2 (9 experts each, hi/lo bf16 packed) then routing arrays
  u32* P1 = (u32*)d_ws;
  u32* P3 = P1 + (size_t)9 * PERMAT;
  u32* P2 = P3 + (size_t)9 * PERMAT;
  int*   cnt  = (int*)(P2 + (size_t)9 * PERMAT);
  int*   cur  = cnt + 16;
  int*   offs = cur + 16;
  int*   idx  = offs + 16;
  float* wgt  = (float*)(idx + 2 * T);
  int*   tokl = (int*)(wgt + 2 * T);
  float* wof  = (float*)(tokl + 2 * T);

  const size_t smem = (size_t)(2 * 6144 + 2 * 12288 + MROWS + MROWS) * 4;  // 147,840 B
  hipFuncSetAttribute(reinterpret_cast<const void*>(expert_mfma<true>),
                      hipFuncAttributeMaxDynamicSharedMemorySize, (int)smem);
  hipFuncSetAttribute(reinterpret_cast<const void*>(expert_mfma<false>),
                      hipFuncAttributeMaxDynamicSharedMemorySize, (int)smem);

  init_kernel<<<1, 64, 0, stream>>>(cnt, cur);
  prep_kernel<<<5184, 256, 0, stream>>>(w1, w3, w2, sw1, sw3, sw2, P1, P3, P2);
  gate_kernel<<<(T + 3) / 4, 256, 0, stream>>>(x, gw, gb, idx, wgt, cnt, T);
  scan_kernel<<<1, 64, 0, stream>>>(cnt, offs);
  scatter_kernel<<<(T + 255) / 256, 256, 0, stream>>>(idx, wgt, offs, cur, tokl, wof, T);

  const int tpe = (T + MROWS - 1) / MROWS;     // 342 tiles per expert
  // shared expert first: plain stores initialize out over the 0xAA poison
  expert_mfma<true ><<<tpe, 512, smem, stream>>>(x, P1, P3, P2,
      nullptr, nullptr, nullptr, nullptr, out, T, 0, tpe, tpe);
  // routed: slot 0 then slot 1 (stream-ordered -> race-free RMW)
  expert_mfma<false><<<NE * tpe, 512, smem, stream>>>(x, P1, P3, P2,
      cnt, offs, tokl, wof, out, T, 0, tpe, NE * tpe);
  expert_mfma<false><<<NE * tpe, 512, smem, stream>>>(x, P1, P3, P2,
      cnt, offs, tokl, wof, out, T, 1, tpe, NE * tpe);
}

// Round 5
// 662.004 us; speedup vs baseline: 1.6312x; 1.6312x over previous
//
#include <hip/hip_runtime.h>
#include <math.h>

#define DIM_  768
#define INT_  512
#define NE    8
#define MROWS 48                 // tokens per tile
#define PERMAT 393216            // u32s per (expert,matrix): 768 frags * 64 lanes * 8

typedef unsigned int u32;
typedef unsigned short u16;
typedef __attribute__((ext_vector_type(4))) u32   u32x4;
typedef __attribute__((ext_vector_type(8))) short bf16x8;
typedef __attribute__((ext_vector_type(4))) float f32x4;

#define MFMA(acc, a, b) acc = __builtin_amdgcn_mfma_f32_16x16x32_bf16(a, b, acc, 0, 0, 0)

static __device__ __forceinline__ u16 f2bf(float f) {      // RNE float->bf16
  u32 u = __builtin_bit_cast(u32, f);
  return (u16)((u + 0x7fffu + ((u >> 16) & 1u)) >> 16);
}
static __device__ __forceinline__ float bf2f(u16 s) {
  u32 u = ((u32)s) << 16; return __builtin_bit_cast(float, u);
}
// swizzled word offset in a [rows][L u32] LDS plane; XOR on 16B granules,
// bijective within each row, identical at write & read -> correctness-neutral
template<int L>
static __device__ __forceinline__ int swoff(int row, int wi) {
  int g = (wi >> 2) ^ ((row & 7) << 1);
  return row * L + ((g & (L / 4 - 1)) << 2) + (wi & 3);
}

// ---------------------------------------------------------------------------
// ROUTING — atomic-free (two-level histogram + deterministic scatter).
// gate: thread-per-token; gw read via wave-uniform addresses (scalar loads);
// top-k register-only; per-block LDS histogram -> bh[block][16] plain store.
// ---------------------------------------------------------------------------
__global__ __launch_bounds__(256)
void gate_kernel(const float* __restrict__ x, const float* __restrict__ gw,
                 const float* __restrict__ gb, int* __restrict__ pidx,
                 float* __restrict__ wgt, int* __restrict__ bh, int T) {
  __shared__ int hist[16];
  const int tid = threadIdx.x;
  if (tid < 16) hist[tid] = 0;
  __syncthreads();
  const int t = blockIdx.x * 256 + tid;
  if (t < T) {
    float acc[NE] = {};
    const float* xr = x + (size_t)t * DIM_;
    for (int k0 = 0; k0 < DIM_; k0 += 8) {
      float4 xa = *(const float4*)&xr[k0];
      float4 xb = *(const float4*)&xr[k0 + 4];
#pragma unroll
      for (int e = 0; e < NE; ++e) {
        const float* g8 = &gw[e * DIM_ + k0];   // uniform address -> s_load
        acc[e] = fmaf(xa.x, g8[0], acc[e]);
        acc[e] = fmaf(xa.y, g8[1], acc[e]);
        acc[e] = fmaf(xa.z, g8[2], acc[e]);
        acc[e] = fmaf(xa.w, g8[3], acc[e]);
        acc[e] = fmaf(xb.x, g8[4], acc[e]);
        acc[e] = fmaf(xb.y, g8[5], acc[e]);
        acc[e] = fmaf(xb.z, g8[6], acc[e]);
        acc[e] = fmaf(xb.w, g8[7], acc[e]);
      }
    }
    // selection: all arrays compile-time indexed (registers only)
    float sc[NE], s[NE];
#pragma unroll
    for (int e = 0; e < NE; ++e) {
      sc[e] = 1.0f / (1.0f + expf(-acc[e]));    // original sigmoid scores
      s[e]  = sc[e] + gb[e];                    // bias affects selection only
    }
    float gsc[4];
#pragma unroll
    for (int g = 0; g < 4; ++g) gsc[g] = s[2*g] + s[2*g+1];  // top2-of-2 = sum
    int g1 = 0; float b1v = gsc[0];
#pragma unroll
    for (int g = 1; g < 4; ++g) if (gsc[g] > b1v) { b1v = gsc[g]; g1 = g; }
    int g2 = (g1 == 0) ? 1 : 0;
    float b2v = (g1 == 0) ? gsc[1] : gsc[0];
#pragma unroll
    for (int g = 0; g < 4; ++g)
      if ((g != g1) && (gsc[g] > b2v)) { b2v = gsc[g]; g2 = g; }
    unsigned mask = (3u << (2*g1)) | (3u << (2*g2));
    int e1 = -1; float bs1 = -3.0e38f;
#pragma unroll
    for (int e = 0; e < NE; ++e) {
      bool in = (mask >> e) & 1u;
      if (in && (s[e] > bs1)) { bs1 = s[e]; e1 = e; }   // first-wins ties
    }
    int e2 = -1; float bs2 = -3.0e38f;
#pragma unroll
    for (int e = 0; e < NE; ++e) {
      bool in = ((mask >> e) & 1u) && (e != e1);
      if (in && (s[e] > bs2)) { bs2 = s[e]; e2 = e; }
    }
    float wa = 0.f, wb = 0.f;
#pragma unroll
    for (int e = 0; e < NE; ++e) {
      if (e == e1) wa = sc[e];
      if (e == e2) wb = sc[e];
    }
    float inv = 1.0f / (wa + wb + 1e-6f);       // ROUTE_SCALE = 1
    wa *= inv; wb *= inv;
    pidx[t] = e1 | (e2 << 8);
    wgt[2*t] = wa; wgt[2*t+1] = wb;
    atomicAdd(&hist[e1], 1);                    // LDS atomics only
    atomicAdd(&hist[8 + e2], 1);
  }
  __syncthreads();
  if (tid < 16) bh[blockIdx.x * 16 + tid] = hist[tid];
}

// one block; converts bh to exact per-block bases in-place, writes cnt/offs
__global__ void scan_kernel(int* __restrict__ bh, int* __restrict__ cnt,
                            int* __restrict__ offs, int NB) {
  __shared__ int colsum[16], base_s[16];
  const int tid = threadIdx.x;
  if (tid < 16) {
    int s = 0;
    for (int b = 0; b < NB; ++b) {
      int v = bh[b * 16 + tid];
      bh[b * 16 + tid] = s;                     // local exclusive prefix
      s += v;
    }
    colsum[tid] = s;
  }
  __syncthreads();
  if (tid == 0) {
    int a = 0;
    for (int L = 0; L < 16; ++L) {
      base_s[L] = a; offs[L] = a; cnt[L] = colsum[L]; a += colsum[L];
    }
  }
  __syncthreads();
  if (tid < 16) {
    int add = base_s[tid];
    for (int b = 0; b < NB; ++b) bh[b * 16 + tid] += add;
  }
}

// deterministic placement: block base from bh + LDS cursor (no global atomics)
__global__ __launch_bounds__(256)
void scatter_kernel(const int* __restrict__ pidx, const float* __restrict__ wgt,
                    const int* __restrict__ bh, int* __restrict__ tok,
                    float* __restrict__ wof, int T) {
  __shared__ int lcur[16];
  const int tid = threadIdx.x;
  if (tid < 16) lcur[tid] = bh[blockIdx.x * 16 + tid];
  __syncthreads();
  const int t = blockIdx.x * 256 + tid;
  if (t < T) {
    int pi = pidx[t];
    int e1 = pi & 255, e2 = (pi >> 8) & 255;
    int p0 = atomicAdd(&lcur[e1], 1);
    tok[p0] = t; wof[p0] = wgt[2*t];
    int p1 = atomicAdd(&lcur[8 + e2], 1);
    tok[p1] = t; wof[p1] = wgt[2*t+1];
  }
}

// ---------------------------------------------------------------------------
// prep: split fp32 weights into hi/lo bf16 and pack fragment-major.
// Fragment (lane l): col = nb*16 + (l&15), k = ks*32 + (l>>4)*8 + j (j=0..7).
// Per lane: 4 u32 hi then 4 u32 lo. Experts 0..7 routed, 8 = shared MLP.
// ---------------------------------------------------------------------------
__global__ __launch_bounds__(256)
void prep_kernel(const float* __restrict__ w1, const float* __restrict__ w3,
                 const float* __restrict__ w2, const float* __restrict__ sw1,
                 const float* __restrict__ sw3, const float* __restrict__ sw2,
                 u32* __restrict__ P1, u32* __restrict__ P3, u32* __restrict__ P2) {
  const int PER = 9 * 768 * 64;
  int gid = blockIdx.x * 256 + threadIdx.x;
  int which = gid / PER;
  int r = gid % PER;
  int lane = r & 63;
  int fe = r >> 6;
  int fs = fe % 768;
  int e  = fe / 768;
  int c16 = lane & 15, q = lane >> 4;

  const float* src; u32* dst;
  if (which < 2) {                              // w1 / w3: [512 cols][768 k]
    int nb = fs / 24, ks = fs % 24;
    int col = nb * 16 + c16, k0 = ks * 32 + q * 8;
    const float* wm = (which == 0) ? w1 : w3;
    const float* sm = (which == 0) ? sw1 : sw3;
    src = (e < 8) ? wm + ((size_t)e * INT_ + col) * DIM_ + k0
                  : sm + (size_t)col * DIM_ + k0;
    dst = ((which == 0) ? P1 : P3) + ((size_t)(e * 768 + fs) * 64 + lane) * 8;
  } else {                                      // w2: [768 cols][512 k]
    int nb = fs / 16, ks = fs % 16;
    int col = nb * 16 + c16, k0 = ks * 32 + q * 8;
    src = (e < 8) ? w2 + ((size_t)e * DIM_ + col) * INT_ + k0
                  : sw2 + (size_t)col * INT_ + k0;
    dst = P2 + ((size_t)(e * 768 + fs) * 64 + lane) * 8;
  }
  float4 a = *(const float4*)src;
  float4 b = *(const float4*)(src + 4);
  u16 h0=f2bf(a.x), h1=f2bf(a.y), h2=f2bf(a.z), h3=f2bf(a.w);
  u16 h4=f2bf(b.x), h5=f2bf(b.y), h6=f2bf(b.z), h7=f2bf(b.w);
  u32x4 H = { (u32)h0|((u32)h1<<16), (u32)h2|((u32)h3<<16),
              (u32)h4|((u32)h5<<16), (u32)h6|((u32)h7<<16) };
  u32x4 Lv = { (u32)f2bf(a.x-bf2f(h0)) | ((u32)f2bf(a.y-bf2f(h1))<<16),
               (u32)f2bf(a.z-bf2f(h2)) | ((u32)f2bf(a.w-bf2f(h3))<<16),
               (u32)f2bf(b.x-bf2f(h4)) | ((u32)f2bf(b.y-bf2f(h5))<<16),
               (u32)f2bf(b.z-bf2f(h6)) | ((u32)f2bf(b.w-bf2f(h7))<<16) };
  *(u32x4*)dst = H;
  *(u32x4*)(dst + 4) = Lv;
}

// ---------------------------------------------------------------------------
// Fused SwiGLU expert, split-bf16 MFMA (D = Ah·Bh + Al·Bh + Ah·Bl, fp32 acc).
// 48-token tile, 8 waves. LDS: Xh/Xl[48][128u32] + Hh/Hl[48][256u32] ~147.8KB.
// ---------------------------------------------------------------------------
template<bool SHARED>
__global__ __launch_bounds__(512, 2)
void expert_mfma(const float* __restrict__ x,
                 const u32* __restrict__ P1, const u32* __restrict__ P3,
                 const u32* __restrict__ P2,
                 const int* __restrict__ cnt, const int* __restrict__ offs,
                 const int* __restrict__ tok, const float* __restrict__ wof,
                 float* __restrict__ out, int T, int slot, int tpe, int nwg) {
  extern __shared__ u32 sm[];
  u32* Xh = sm;                    // 48*128
  u32* Xl = Xh + 6144;
  u32* Hh = Xl + 6144;             // 48*256
  u32* Hl = Hh + 12288;
  int*   rts_s = (int*)(Hl + 12288);
  float* wrs_s = (float*)(rts_s + MROWS);

  // bijective XCD-chunked remap (m204)
  int orig = blockIdx.x;
  int q8 = nwg >> 3, rr = nwg & 7, xcd = orig & 7, pos = orig >> 3;
  int wgid = (xcd < rr ? xcd * (q8 + 1) : rr * (q8 + 1) + (xcd - rr) * q8) + pos;

  int e, n, off0, tile;
  if (SHARED) { e = 8; tile = wgid; n = T; off0 = 0; }
  else {
    e = wgid / tpe; tile = wgid % tpe;
    int L = slot * 8 + e;
    n = cnt[L]; off0 = offs[L];
  }
  const int r0 = tile * MROWS;
  if (r0 >= n) return;
  const int nr = min(MROWS, n - r0);
  const int tid = threadIdx.x;

  if (tid < MROWS) {
    int r = r0 + tid;
    if (SHARED) { rts_s[tid] = min(r, T - 1); wrs_s[tid] = 1.0f; }
    else {
      int rc = min(r, n - 1);
      rts_s[tid] = tok[off0 + rc];
      wrs_s[tid] = (r < n) ? wof[off0 + r] : 0.0f;
    }
  }
  __syncthreads();

  const int lane = tid & 63, wid = tid >> 6;
  const int c16 = lane & 15, q = lane >> 4;
  const u32* P1e = P1 + (size_t)e * PERMAT;
  const u32* P3e = P3 + (size_t)e * PERMAT;
  const u32* P2e = P2 + (size_t)e * PERMAT;

  // ---------------- phase 1 ----------------
  f32x4 acc1[3][4] = {};
  f32x4 acc3[3][4] = {};
  for (int ch = 0; ch < 3; ++ch) {
    __syncthreads();
    {
      const int cb = ch * 256;
#pragma unroll
      for (int u = 0; u < 6; ++u) {             // 3072 float4: 48 rows x 64
        int f = u * 512 + tid;
        int row = f >> 6, kq = f & 63;
        float4 v = *(const float4*)&x[(size_t)rts_s[row] * DIM_ + cb + kq * 4];
        u16 a0 = f2bf(v.x), a1 = f2bf(v.y), a2 = f2bf(v.z), a3 = f2bf(v.w);
        int base = swoff<128>(row, kq * 2);
        Xh[base]     = (u32)a0 | ((u32)a1 << 16);
        Xh[base + 1] = (u32)a2 | ((u32)a3 << 16);
        Xl[base]     = (u32)f2bf(v.x - bf2f(a0)) | ((u32)f2bf(v.y - bf2f(a1)) << 16);
        Xl[base + 1] = (u32)f2bf(v.z - bf2f(a2)) | ((u32)f2bf(v.w - bf2f(a3)) << 16);
      }
    }
    __syncthreads();
    for (int ks = 0; ks < 8; ++ks) {
      bf16x8 Ah[3], Al[3];
#pragma unroll
      for (int m = 0; m < 3; ++m) {
        int row = 16 * m + c16;
        int wi = ks * 16 + q * 4;
        Ah[m] = __builtin_bit_cast(bf16x8, *(const u32x4*)&Xh[swoff<128>(row, wi)]);
        Al[m] = __builtin_bit_cast(bf16x8, *(const u32x4*)&Xl[swoff<128>(row, wi)]);
      }
      const int gks = ch * 8 + ks;
#pragma unroll
      for (int nf = 0; nf < 4; ++nf) {
        int nb = wid * 4 + nf;
        const u32* p1 = P1e + ((size_t)(nb * 24 + gks) * 64 + lane) * 8;
        const u32* p3 = P3e + ((size_t)(nb * 24 + gks) * 64 + lane) * 8;
        bf16x8 B1h = __builtin_bit_cast(bf16x8, *(const u32x4*)p1);
        bf16x8 B1l = __builtin_bit_cast(bf16x8, *(const u32x4*)(p1 + 4));
        bf16x8 B3h = __builtin_bit_cast(bf16x8, *(const u32x4*)p3);
        bf16x8 B3l = __builtin_bit_cast(bf16x8, *(const u32x4*)(p3 + 4));
#pragma unroll
        for (int m = 0; m < 3; ++m) {
          MFMA(acc1[m][nf], Ah[m], B1h);
          MFMA(acc1[m][nf], Al[m], B1h);
          MFMA(acc1[m][nf], Ah[m], B1l);
          MFMA(acc3[m][nf], Ah[m], B3h);
          MFMA(acc3[m][nf], Al[m], B3h);
          MFMA(acc3[m][nf], Ah[m], B3l);
        }
      }
    }
  }
  // phase-1 epilogue: h = silu(a1)*a3, split hi/lo into Hs planes
  {
    u16* Hh16 = (u16*)Hh;
    u16* Hl16 = (u16*)Hl;
#pragma unroll
    for (int m = 0; m < 3; ++m)
#pragma unroll
      for (int nf = 0; nf < 4; ++nf)
#pragma unroll
        for (int reg = 0; reg < 4; ++reg) {
          int tokr = 16 * m + 4 * q + reg;            // C/D: row=(l>>4)*4+reg
          int col  = (wid * 4 + nf) * 16 + c16;       //       col=l&15
          float v1 = acc1[m][nf][reg], v3 = acc3[m][nf][reg];
          float h = v1 / (1.0f + expf(-v1)) * v3;
          u16 hh = f2bf(h);
          u16 hl = f2bf(h - bf2f(hh));
          int wo = swoff<256>(tokr, col >> 1);
          Hh16[wo * 2 + (col & 1)] = hh;
          Hl16[wo * 2 + (col & 1)] = hl;
        }
  }
  __syncthreads();

  // ---------------- phase 2 ----------------
  f32x4 acc2[3][6] = {};
  for (int ks = 0; ks < 16; ++ks) {
    bf16x8 Ah[3], Al[3];
#pragma unroll
    for (int m = 0; m < 3; ++m) {
      int row = 16 * m + c16;
      int wi = ks * 16 + q * 4;
      Ah[m] = __builtin_bit_cast(bf16x8, *(const u32x4*)&Hh[swoff<256>(row, wi)]);
      Al[m] = __builtin_bit_cast(bf16x8, *(const u32x4*)&Hl[swoff<256>(row, wi)]);
    }
#pragma unroll
    for (int nf = 0; nf < 6; ++nf) {
      int nb = wid * 6 + nf;
      const u32* p2 = P2e + ((size_t)(nb * 16 + ks) * 64 + lane) * 8;
      bf16x8 Bh = __builtin_bit_cast(bf16x8, *(const u32x4*)p2);
      bf16x8 Bl = __builtin_bit_cast(bf16x8, *(const u32x4*)(p2 + 4));
#pragma unroll
      for (int m = 0; m < 3; ++m) {
        MFMA(acc2[m][nf], Ah[m], Bh);
        MFMA(acc2[m][nf], Al[m], Bh);
        MFMA(acc2[m][nf], Ah[m], Bl);
      }
    }
  }
  // epilogue: scale by combine weight; SHARED plain-stores (init), routed RMW
#pragma unroll
  for (int m = 0; m < 3; ++m)
#pragma unroll
    for (int reg = 0; reg < 4; ++reg) {
      int tr = 16 * m + 4 * q + reg;
      if (tr < nr) {
        int gt = rts_s[tr];
        float wv = wrs_s[tr];
        float* po = out + (size_t)gt * DIM_ + c16;
#pragma unroll
        for (int nf = 0; nf < 6; ++nf) {
          int col = (wid * 6 + nf) * 16;
          float val = acc2[m][nf][reg] * wv;
          if (SHARED) po[col] = val;
          else        po[col] += val;           // race-free: slot launches serialized
        }
      }
    }
}

// ---------------------------------------------------------------------------
extern "C" void kernel_launch(void* const* d_in, const int* in_sizes, int n_in,
                              void* d_out, int out_size, void* d_ws, size_t ws_size,
                              hipStream_t stream) {
  const float* x   = (const float*)d_in[0];
  const float* gw  = (const float*)d_in[1];
  const float* gb  = (const float*)d_in[2];
  const float* w1  = (const float*)d_in[3];
  const float* w2  = (const float*)d_in[4];
  const float* w3  = (const float*)d_in[5];
  const float* sw1 = (const float*)d_in[6];
  const float* sw2 = (const float*)d_in[7];
  const float* sw3 = (const float*)d_in[8];
  float* out = (float*)d_out;
  const int T = in_sizes[0] / DIM_;            // 16384
  const int NB = (T + 255) / 256;              // 64 gate/scatter blocks

  // ws: P1|P3|P2 | bh[NB*16] | cnt[16] | offs[16] | pidx[T] | wgt[2T] | tok[2T] | wof[2T]
  u32* P1 = (u32*)d_ws;
  u32* P3 = P1 + (size_t)9 * PERMAT;
  u32* P2 = P3 + (size_t)9 * PERMAT;
  int*   bh   = (int*)(P2 + (size_t)9 * PERMAT);
  int*   cnt  = bh + NB * 16;
  int*   offs = cnt + 16;
  int*   pidx = offs + 16;
  float* wgt  = (float*)(pidx + T);
  int*   tokl = (int*)(wgt + 2 * T);
  float* wof  = (float*)(tokl + 2 * T);

  const size_t smem = (size_t)(2 * 6144 + 2 * 12288 + MROWS + MROWS) * 4;  // 147,840 B
  hipFuncSetAttribute(reinterpret_cast<const void*>(expert_mfma<true>),
                      hipFuncAttributeMaxDynamicSharedMemorySize, (int)smem);
  hipFuncSetAttribute(reinterpret_cast<const void*>(expert_mfma<false>),
                      hipFuncAttributeMaxDynamicSharedMemorySize, (int)smem);

  prep_kernel<<<5184, 256, 0, stream>>>(w1, w3, w2, sw1, sw3, sw2, P1, P3, P2);
  gate_kernel<<<NB, 256, 0, stream>>>(x, gw, gb, pidx, wgt, bh, T);
  scan_kernel<<<1, 64, 0, stream>>>(bh, cnt, offs, NB);
  scatter_kernel<<<NB, 256, 0, stream>>>(pidx, wgt, bh, tokl, wof, T);

  const int tpe = (T + MROWS - 1) / MROWS;     // 342 tiles per expert
  // shared expert first: plain stores initialize out over the 0xAA poison
  expert_mfma<true ><<<tpe, 512, smem, stream>>>(x, P1, P3, P2,
      nullptr, nullptr, nullptr, nullptr, out, T, 0, tpe, tpe);
  // routed: slot 0 then slot 1 (stream-ordered -> race-free RMW)
  expert_mfma<false><<<NE * tpe, 512, smem, stream>>>(x, P1, P3, P2,
      cnt, offs, tokl, wof, out, T, 0, tpe, NE * tpe);
  expert_mfma<false><<<NE * tpe, 512, smem, stream>>>(x, P1, P3, P2,
      cnt, offs, tokl, wof, out, T, 1, tpe, NE * tpe);
}